// Round 2
// baseline (92.584 us; speedup 1.0000x reference)
//
#include <hip/hip_runtime.h>

// TensorProduct: out[b, seg[n], c] += CG[n] * x1[b, M1[n], c] * x2[b, M2[n], c]
// B=128, NUM_M=25, C=128, fp32.
// v2b: 4-wave block per (m_out, b-pair); waves split the segment 4-way (n = lo+w, step 4)
// and LDS-reduce. Raises occupancy ~1.6 -> ~6.25 waves/SIMD to hide the dependent
// index-load -> gather chain that dominated the 1-wave version.
// (v2b: segment bounds computed once by wave 0, broadcast via LDS.)

#define NUM_M  25
#define B_SZ   128
#define C_DIM  128
#define C4     (C_DIM / 4)   // 32 float4 chunks
#define NSPLIT 4             // waves per block, n-interleave factor

__device__ __forceinline__ int wave_lower_bound(const int* __restrict__ seg,
                                                int nnz, int key) {
    const int lane = threadIdx.x & 63;
    int lo = 0, hi = nnz;            // invariant: seg[lo-1] < key <= seg[hi] (sentinels)
    while (hi > lo) {
        const int len = hi - lo;
        const int S = (len + 63) >> 6;          // ceil(len/64)
        const int idx = lo + lane * S;
        bool pred = false;
        if (idx < hi) pred = (seg[idx] < key);
        const unsigned long long bal = __ballot(pred);
        const int c = __popcll(bal);            // first sample >= key is sample #c
        if (c == 0) { hi = lo; break; }         // seg[lo] >= key -> answer = lo
        int nhi = lo + c * S;
        if (nhi > hi) nhi = hi;
        lo = lo + (c - 1) * S + 1;
        hi = nhi;
    }
    return lo;
}

__global__ __launch_bounds__(256) void tp_kernel(
    const float* __restrict__ x1, const float* __restrict__ x2,
    const float* __restrict__ cg, const int* __restrict__ M1,
    const int* __restrict__ M2, const int* __restrict__ seg,
    int nnz, float* __restrict__ out) {

    const int m    = blockIdx.x;          // 0..24  (output M index)
    const int bp   = blockIdx.y;          // 0..63  (batch pair)
    const int tid  = threadIdx.x;         // 0..255
    const int lane = tid & 63;
    const int w    = tid >> 6;            // wave id 0..3
    const int b    = bp * 2 + (lane >> 5);
    const int c4   = lane & 31;

    __shared__ int bounds[2];
    __shared__ float4 red[NSPLIT - 1][64];

    if (w == 0) {
        const int lo0 = wave_lower_bound(seg, nnz, m);
        const int hi0 = wave_lower_bound(seg, nnz, m + 1);
        if (lane == 0) { bounds[0] = lo0; bounds[1] = hi0; }
    }
    __syncthreads();
    const int lo = bounds[0];
    const int hi = bounds[1];

    const float4* __restrict__ x1t = ((const float4*)x1) + b * (NUM_M * C4) + c4;
    const float4* __restrict__ x2t = ((const float4*)x2) + b * (NUM_M * C4) + c4;

    float4 acc = make_float4(0.f, 0.f, 0.f, 0.f);

#pragma unroll 4
    for (int n = lo + w; n < hi; n += NSPLIT) {
        const int   m1 = M1[n];           // wave-uniform
        const int   m2 = M2[n];
        const float wt = cg[n];
        const float4 a  = x1t[m1 * C4];   // coalesced 16B/lane, cache-hot
        const float4 bb = x2t[m2 * C4];
        acc.x = fmaf(wt * a.x, bb.x, acc.x);
        acc.y = fmaf(wt * a.y, bb.y, acc.y);
        acc.z = fmaf(wt * a.z, bb.z, acc.z);
        acc.w = fmaf(wt * a.w, bb.w, acc.w);
    }

    // Cross-wave reduction in LDS (waves 1..3 publish, wave 0 sums + stores)
    if (w > 0) red[w - 1][lane] = acc;
    __syncthreads();
    if (w == 0) {
#pragma unroll
        for (int k = 0; k < NSPLIT - 1; ++k) {
            const float4 r = red[k][lane];
            acc.x += r.x; acc.y += r.y; acc.z += r.z; acc.w += r.w;
        }
        ((float4*)out)[b * (NUM_M * C4) + m * C4 + c4] = acc;
    }
}

extern "C" void kernel_launch(void* const* d_in, const int* in_sizes, int n_in,
                              void* d_out, int out_size, void* d_ws, size_t ws_size,
                              hipStream_t stream) {
    const float* x1  = (const float*)d_in[0];
    const float* x2  = (const float*)d_in[1];
    const float* cg  = (const float*)d_in[2];
    const int*   M1  = (const int*)d_in[3];
    const int*   M2  = (const int*)d_in[4];
    const int*   seg = (const int*)d_in[5];
    const int    nnz = in_sizes[2];
    float* out = (float*)d_out;

    dim3 grid(NUM_M, B_SZ / 2);   // 25 x 64 blocks, 4 waves each
    tp_kernel<<<grid, 256, 0, stream>>>(x1, x2, cg, M1, M2, seg, nnz, out);
}

// Round 3
// 86.650 us; speedup vs baseline: 1.0685x; 1.0685x over previous
//
#include <hip/hip_runtime.h>

// TensorProduct: out[b, seg[n], c] += CG[n] * x1[b, M1[n], c] * x2[b, M2[n], c]
// B=128, NUM_M=25, C=128, fp32.
// v3: 4-wave block per (m_out, b-pair); waves split the segment 4-way (n = lo+w+4k).
// CRITICAL vs v2b: lo/hi/w stay provably wave-uniform (ballot-derived + readfirstlane),
// so M1/M2/cg loads remain SCALAR (s_load, lgkm pipe) and never serialize the VMEM
// gather queue. LDS used only for the final cross-wave reduction.

#define NUM_M  25
#define B_SZ   128
#define C_DIM  128
#define C4     (C_DIM / 4)   // 32 float4 chunks
#define NSPLIT 4             // waves per block, n-interleave factor

__device__ __forceinline__ int wave_lower_bound(const int* __restrict__ seg,
                                                int nnz, int key) {
    const int lane = threadIdx.x & 63;
    int lo = 0, hi = nnz;            // invariant: seg[lo-1] < key <= seg[hi] (sentinels)
    while (hi > lo) {
        const int len = hi - lo;
        const int S = (len + 63) >> 6;          // ceil(len/64)
        const int idx = lo + lane * S;
        bool pred = false;
        if (idx < hi) pred = (seg[idx] < key);
        const unsigned long long bal = __ballot(pred);
        const int c = __popcll(bal);            // first sample >= key is sample #c
        if (c == 0) { hi = lo; break; }         // seg[lo] >= key -> answer = lo
        int nhi = lo + c * S;
        if (nhi > hi) nhi = hi;
        lo = lo + (c - 1) * S + 1;
        hi = nhi;
    }
    return lo;
}

__global__ __launch_bounds__(256) void tp_kernel(
    const float* __restrict__ x1, const float* __restrict__ x2,
    const float* __restrict__ cg, const int* __restrict__ M1,
    const int* __restrict__ M2, const int* __restrict__ seg,
    int nnz, float* __restrict__ out) {

    const int m    = blockIdx.x;          // 0..24  (output M index)
    const int bp   = blockIdx.y;          // 0..63  (batch pair)
    const int tid  = threadIdx.x;         // 0..255
    const int lane = tid & 63;
    // wave id, forced into an SGPR so the n-loop stays scalar
    const int w    = __builtin_amdgcn_readfirstlane(tid >> 6);
    const int b    = bp * 2 + (lane >> 5);
    const int c4   = lane & 31;

    // Each wave computes its own bounds (ballot-derived -> SGPR-uniform; L2-hot)
    const int lo = wave_lower_bound(seg, nnz, m);
    const int hi = wave_lower_bound(seg, nnz, m + 1);

    const float4* __restrict__ x1t = ((const float4*)x1) + b * (NUM_M * C4) + c4;
    const float4* __restrict__ x2t = ((const float4*)x2) + b * (NUM_M * C4) + c4;

    float4 acc = make_float4(0.f, 0.f, 0.f, 0.f);

#pragma unroll 4
    for (int n = lo + w; n < hi; n += NSPLIT) {
        const int   m1 = M1[n];           // wave-uniform -> s_load
        const int   m2 = M2[n];
        const float wt = cg[n];
        const float4 a  = x1t[m1 * C4];   // coalesced 16B/lane, cache-hot
        const float4 bb = x2t[m2 * C4];
        acc.x = fmaf(wt * a.x, bb.x, acc.x);
        acc.y = fmaf(wt * a.y, bb.y, acc.y);
        acc.z = fmaf(wt * a.z, bb.z, acc.z);
        acc.w = fmaf(wt * a.w, bb.w, acc.w);
    }

    // Cross-wave reduction in LDS (waves 1..3 publish, wave 0 sums + stores)
    __shared__ float4 red[NSPLIT - 1][64];
    if (w > 0) red[w - 1][lane] = acc;
    __syncthreads();
    if (w == 0) {
#pragma unroll
        for (int k = 0; k < NSPLIT - 1; ++k) {
            const float4 r = red[k][lane];
            acc.x += r.x; acc.y += r.y; acc.z += r.z; acc.w += r.w;
        }
        ((float4*)out)[b * (NUM_M * C4) + m * C4 + c4] = acc;
    }
}

extern "C" void kernel_launch(void* const* d_in, const int* in_sizes, int n_in,
                              void* d_out, int out_size, void* d_ws, size_t ws_size,
                              hipStream_t stream) {
    const float* x1  = (const float*)d_in[0];
    const float* x2  = (const float*)d_in[1];
    const float* cg  = (const float*)d_in[2];
    const int*   M1  = (const int*)d_in[3];
    const int*   M2  = (const int*)d_in[4];
    const int*   seg = (const int*)d_in[5];
    const int    nnz = in_sizes[2];
    float* out = (float*)d_out;

    dim3 grid(NUM_M, B_SZ / 2);   // 25 x 64 blocks, 4 waves each
    tp_kernel<<<grid, 256, 0, stream>>>(x1, x2, cg, M1, M2, seg, nnz, out);
}